// Round 7
// baseline (137.112 us; speedup 1.0000x reference)
//
#include <hip/hip_runtime.h>

#define B_ 64
#define T_ 2048
#define H_ 512
#define A_ 512

typedef unsigned short u16;
typedef __attribute__((ext_vector_type(8))) short bf16x8;
typedef __attribute__((ext_vector_type(4))) float f32x4;

__device__ __forceinline__ u16 f2bf(float f) {
  unsigned u = __float_as_uint(f);
  unsigned r = (u + 0x7FFFu + ((u >> 16) & 1u)) >> 16;  // RNE
  return (u16)r;
}

__device__ __forceinline__ float bf2f(u16 h) {
  return __uint_as_float(((unsigned)h) << 16);
}

__device__ __forceinline__ float fast_tanh(float x) {
  float e = __expf(2.0f * x);
  return 1.0f - 2.0f * __builtin_amdgcn_rcpf(e + 1.0f);
}

// Barrier that waits ONLY LDS ops: in-flight global loads survive it.
#define BAR_LDS() asm volatile("s_waitcnt lgkmcnt(0)\n\ts_barrier" ::: "memory")

// ---------------- K1: merged W_enc conversion + dec_proj -------------------
__global__ void k_prep(const float* __restrict__ W, u16* __restrict__ wsB,
                       const float* __restrict__ dec, const float* __restrict__ Wd,
                       float* __restrict__ dp) {
  __shared__ float dl[H_];
  int tid = threadIdx.x;
  int bx = blockIdx.x;
  if (bx < 128) {
    int u = bx * 256 + tid;  // 32768 units
    int a = u >> 6;
    int hq = u & 63;
    int ks = hq >> 2;
    int q = hq & 3;
    const float4* src = (const float4*)(W + a * H_ + hq * 8);
    float4 x0 = src[0], x1 = src[1];
    uint4 pk;
    pk.x = (unsigned)f2bf(x0.x) | ((unsigned)f2bf(x0.y) << 16);
    pk.y = (unsigned)f2bf(x0.z) | ((unsigned)f2bf(x0.w) << 16);
    pk.z = (unsigned)f2bf(x1.x) | ((unsigned)f2bf(x1.y) << 16);
    pk.w = (unsigned)f2bf(x1.z) | ((unsigned)f2bf(x1.w) << 16);
    int dst = ks * 2048 + (a >> 4) * 64 + q * 16 + (a & 15);
    ((uint4*)wsB)[dst] = pk;
  } else {
    int e = bx - 128;        // 512 blocks
    int b = e >> 3;
    int a0 = (e & 7) * 64;
    dl[tid] = dec[b * H_ + tid];
    dl[tid + 256] = dec[b * H_ + tid + 256];
    __syncthreads();
    int al = tid >> 2, p = tid & 3;
    const float4* wr = (const float4*)(Wd + (a0 + al) * H_ + p * 128);
    const float4* dv = (const float4*)(dl + p * 128);
    float s = 0.f;
#pragma unroll 8
    for (int i = 0; i < 32; ++i) {
      float4 w4 = wr[i], d4 = dv[i];
      s += w4.x * d4.x + w4.y * d4.y + w4.z * d4.z + w4.w * d4.w;
    }
    s += __shfl_xor(s, 1);
    s += __shfl_xor(s, 2);
    if (p == 0) dp[b * H_ + a0 + al] = s;
  }
}

// ---------------- K2: fused GEMM + tanh + V-dot + local softmax + PV -------
// 2 row-tiles (64 rows each) per block, grid 1024. 8 waves; wave w owns cols
// [w*64, w*64+64). 1 block/CU (130 KB LDS), 256 regs/wave: tile1's global
// loads issued BEFORE compute0 (hidden under ~10k cyc of MFMA); K-loop is
// barrier-free with an explicit depth-2 rolling B prefetch (4 named sets).
// LDS unit u (16B, 8 bf16) = ks*256 + m*64 + q*16 + r
//   holds enc_bf16[row = m*16+r][cols ks*32+q*8 .. +8]
__launch_bounds__(512, 2)
__global__ void k_scores(const float* __restrict__ enc, const u16* __restrict__ wsB,
                         const float* __restrict__ dpj, const float* __restrict__ V,
                         float* __restrict__ scores, float* __restrict__ part,
                         float* __restrict__ mz) {
  __shared__ __attribute__((aligned(16))) u16 Ab[2][64 * 512];  // 128 KB
  __shared__ float red[8][64];
  int tid = threadIdx.x;
  int w = tid >> 6, l = tid & 63;
  int q = l >> 4, r = l & 15;
  int tile0 = blockIdx.x * 2;
  int m0 = tile0 * 64;
  int b = m0 >> 11;  // 16 blocks (128 rows) per batch, same b for both tiles

  // staging decode: thread owns unit it*512+tid for it=0..7
  int rem = tid & 255;
  int sm = rem >> 6, sq = (rem >> 4) & 3, sr = rem & 15;
  int half = tid >> 8;
  const float* ab0 = enc + (size_t)(m0 + sm * 16 + sr) * H_ + half * 32 + sq * 8;
  const float* ab1 = ab0 + (size_t)64 * H_;

  // hoisted epilogue constants (same cols for both tiles)
  float vv[4], dd[4];
  const float* db = dpj + b * A_;
#pragma unroll
  for (int n = 0; n < 4; ++n) {
    int col = w * 64 + n * 16 + r;
    vv[n] = V[col];
    dd[n] = db[col];
  }

  const bf16x8* bfrag = (const bf16x8*)wsB;

#define PACK_WRITE(dstAb, y0, y1, it)                                 \
  {                                                                   \
    uint4 pk;                                                         \
    pk.x = (unsigned)f2bf(y0.x) | ((unsigned)f2bf(y0.y) << 16);       \
    pk.y = (unsigned)f2bf(y0.z) | ((unsigned)f2bf(y0.w) << 16);       \
    pk.z = (unsigned)f2bf(y1.x) | ((unsigned)f2bf(y1.y) << 16);       \
    pk.w = (unsigned)f2bf(y1.z) | ((unsigned)f2bf(y1.w) << 16);       \
    ((uint4*)(dstAb))[(it) * 512 + tid] = pk;                         \
  }

#define LOADB(dst, ks)                                                \
  {                                                                   \
    _Pragma("unroll") for (int n = 0; n < 4; ++n)                     \
        dst[n] = bfrag[(ks) * 2048 + (w * 4 + n) * 64 + l];           \
  }

#define KSTEP(AbT, accv, ks, scur, spre)                              \
  {                                                                   \
    if ((ks) < 14) LOADB(spre, (ks) + 2)                              \
    bf16x8 af[4];                                                     \
    _Pragma("unroll") for (int m = 0; m < 4; ++m)                     \
        af[m] = *((const bf16x8*)&(AbT)[((ks)*256 + m * 64 + l) * 8]);\
    __builtin_amdgcn_s_setprio(1);                                    \
    _Pragma("unroll") for (int m = 0; m < 4; ++m)                     \
        _Pragma("unroll") for (int n = 0; n < 4; ++n)                 \
            accv[m][n] = __builtin_amdgcn_mfma_f32_16x16x32_bf16(     \
                af[m], scur[n], accv[m][n], 0, 0, 0);                 \
    __builtin_amdgcn_s_setprio(0);                                    \
  }

#define COMPUTE_TILE(AbT, accv)                                       \
  {                                                                   \
    bf16x8 s0[4], s1[4], s2[4], s3[4];                                \
    LOADB(s0, 0) LOADB(s1, 1)                                         \
    KSTEP(AbT, accv, 0, s0, s2) KSTEP(AbT, accv, 1, s1, s3)           \
    KSTEP(AbT, accv, 2, s2, s0) KSTEP(AbT, accv, 3, s3, s1)           \
    KSTEP(AbT, accv, 4, s0, s2) KSTEP(AbT, accv, 5, s1, s3)           \
    KSTEP(AbT, accv, 6, s2, s0) KSTEP(AbT, accv, 7, s3, s1)           \
    KSTEP(AbT, accv, 8, s0, s2) KSTEP(AbT, accv, 9, s1, s3)           \
    KSTEP(AbT, accv, 10, s2, s0) KSTEP(AbT, accv, 11, s3, s1)         \
    KSTEP(AbT, accv, 12, s0, s2) KSTEP(AbT, accv, 13, s1, s3)         \
    KSTEP(AbT, accv, 14, s2, s0) KSTEP(AbT, accv, 15, s3, s1)         \
  }

#define EPILOGUE(AbT, accv, tile, m0t)                                        \
  {                                                                           \
    float sp[4][4];                                                           \
    _Pragma("unroll") for (int m = 0; m < 4; ++m)                             \
        _Pragma("unroll") for (int j = 0; j < 4; ++j) sp[m][j] = 0.f;         \
    _Pragma("unroll") for (int n = 0; n < 4; ++n) {                           \
      _Pragma("unroll") for (int m = 0; m < 4; ++m)                           \
          _Pragma("unroll") for (int j = 0; j < 4; ++j)                       \
              sp[m][j] = fmaf(vv[n], fast_tanh(accv[m][n][j] + dd[n]),        \
                              sp[m][j]);                                      \
    }                                                                         \
    _Pragma("unroll") for (int m = 0; m < 4; ++m)                             \
        _Pragma("unroll") for (int j = 0; j < 4; ++j) {                       \
      float v_ = sp[m][j];                                                    \
      v_ += __shfl_xor(v_, 1); v_ += __shfl_xor(v_, 2);                       \
      v_ += __shfl_xor(v_, 4); v_ += __shfl_xor(v_, 8);                       \
      sp[m][j] = v_;                                                          \
    }                                                                         \
    float outv = 0.f;                                                         \
    _Pragma("unroll") for (int mm = 0; mm < 4; ++mm)                          \
        _Pragma("unroll") for (int jj = 0; jj < 4; ++jj)                      \
            if (r == mm * 4 + jj) outv = sp[mm][jj];                          \
    BAR_LDS();                                                                \
    red[w][(r >> 2) * 16 + q * 4 + (r & 3)] = outv;                           \
    BAR_LDS();                                                                \
    float s_ = 0.f;                                                           \
    _Pragma("unroll") for (int ww = 0; ww < 8; ++ww) s_ += red[ww][l];        \
    if (w == 0) scores[(m0t) + l] = s_;                                       \
    float mx_ = s_;                                                           \
    _Pragma("unroll") for (int off = 1; off <= 32; off <<= 1)                 \
        mx_ = fmaxf(mx_, __shfl_xor(mx_, off));                               \
    float e_ = __expf(s_ - mx_);                                              \
    float Z_ = e_;                                                            \
    _Pragma("unroll") for (int off = 1; off <= 32; off <<= 1)                 \
        Z_ += __shfl_xor(Z_, off);                                            \
    if (tid == 0) { mz[(tile) * 2] = mx_; mz[(tile) * 2 + 1] = Z_; }          \
    float em[4];                                                              \
    _Pragma("unroll") for (int m = 0; m < 4; ++m)                             \
        em[m] = __shfl(e_, m * 16 + r);                                       \
    float pv0[8], pv1[8];                                                     \
    _Pragma("unroll") for (int j = 0; j < 8; ++j) { pv0[j] = 0.f; pv1[j] = 0.f; } \
    _Pragma("unroll") for (int ksl = 0; ksl < 2; ++ksl) {                     \
      int ks_ = 2 * w + ksl;                                                  \
      _Pragma("unroll") for (int m = 0; m < 4; ++m) {                         \
        uint4 pk = ((const uint4*)(AbT))[ks_ * 256 + m * 64 + l];             \
        float er = em[m];                                                     \
        float v0_ = bf2f((u16)(pk.x & 0xffff)), v1_ = bf2f((u16)(pk.x >> 16));\
        float v2_ = bf2f((u16)(pk.y & 0xffff)), v3_ = bf2f((u16)(pk.y >> 16));\
        float v4_ = bf2f((u16)(pk.z & 0xffff)), v5_ = bf2f((u16)(pk.z >> 16));\
        float v6_ = bf2f((u16)(pk.w & 0xffff)), v7_ = bf2f((u16)(pk.w >> 16));\
        if (ksl == 0) {                                                       \
          pv0[0] = fmaf(er, v0_, pv0[0]); pv0[1] = fmaf(er, v1_, pv0[1]);     \
          pv0[2] = fmaf(er, v2_, pv0[2]); pv0[3] = fmaf(er, v3_, pv0[3]);     \
          pv0[4] = fmaf(er, v4_, pv0[4]); pv0[5] = fmaf(er, v5_, pv0[5]);     \
          pv0[6] = fmaf(er, v6_, pv0[6]); pv0[7] = fmaf(er, v7_, pv0[7]);     \
        } else {                                                              \
          pv1[0] = fmaf(er, v0_, pv1[0]); pv1[1] = fmaf(er, v1_, pv1[1]);     \
          pv1[2] = fmaf(er, v2_, pv1[2]); pv1[3] = fmaf(er, v3_, pv1[3]);     \
          pv1[4] = fmaf(er, v4_, pv1[4]); pv1[5] = fmaf(er, v5_, pv1[5]);     \
          pv1[6] = fmaf(er, v6_, pv1[6]); pv1[7] = fmaf(er, v7_, pv1[7]);     \
        }                                                                     \
      }                                                                       \
    }                                                                         \
    _Pragma("unroll") for (int j = 0; j < 8; ++j) {                           \
      float a0 = pv0[j], a1 = pv1[j];                                         \
      a0 += __shfl_xor(a0, 1); a1 += __shfl_xor(a1, 1);                       \
      a0 += __shfl_xor(a0, 2); a1 += __shfl_xor(a1, 2);                       \
      a0 += __shfl_xor(a0, 4); a1 += __shfl_xor(a1, 4);                       \
      a0 += __shfl_xor(a0, 8); a1 += __shfl_xor(a1, 8);                       \
      pv0[j] = a0; pv1[j] = a1;                                               \
    }                                                                         \
    float ov = 0.f;                                                           \
    _Pragma("unroll") for (int jj = 0; jj < 8; ++jj) {                        \
      if (r == jj) ov = pv0[jj];                                              \
      if (r == jj + 8) ov = pv1[jj];                                          \
    }                                                                         \
    int col_ = w * 64 + (r >> 3) * 32 + q * 8 + (r & 7);                      \
    part[(size_t)(tile) * 512 + col_] = ov;                                   \
  }

  // ---- STAGE tile0 (burst: 16 loads, 8 cvt+writes, counted vmcnt) ----
  {
    float4 xs[16];
#pragma unroll
    for (int it = 0; it < 8; ++it) {
      xs[2 * it] = *((const float4*)(ab0 + it * 64));
      xs[2 * it + 1] = *((const float4*)(ab0 + it * 64 + 4));
    }
#pragma unroll
    for (int it = 0; it < 8; ++it) PACK_WRITE(Ab[0], xs[2 * it], xs[2 * it + 1], it)
  }
  BAR_LDS();

  // ---- issue tile1's global loads EARLY (hidden under compute0) ----
  float4 xs1[16];
#pragma unroll
  for (int it = 0; it < 8; ++it) {
    xs1[2 * it] = *((const float4*)(ab1 + it * 64));
    xs1[2 * it + 1] = *((const float4*)(ab1 + it * 64 + 4));
  }

  // ---- compute tile0 (barrier-free, depth-2 B prefetch) ----
  f32x4 acc0[4][4];
#pragma unroll
  for (int m = 0; m < 4; ++m)
#pragma unroll
    for (int n = 0; n < 4; ++n) acc0[m][n] = (f32x4){0.f, 0.f, 0.f, 0.f};
  COMPUTE_TILE(Ab[0], acc0)

  // ---- write tile1 into LDS (loads landed long ago) ----
#pragma unroll
  for (int it = 0; it < 8; ++it) PACK_WRITE(Ab[1], xs1[2 * it], xs1[2 * it + 1], it)
  BAR_LDS();

  // ---- epilogue tile0 (scores, local softmax, PV) ----
  EPILOGUE(Ab[0], acc0, tile0, m0)

  // ---- compute + epilogue tile1 ----
  f32x4 acc1[4][4];
#pragma unroll
  for (int m = 0; m < 4; ++m)
#pragma unroll
    for (int n = 0; n < 4; ++n) acc1[m][n] = (f32x4){0.f, 0.f, 0.f, 0.f};
  COMPUTE_TILE(Ab[1], acc1)
  EPILOGUE(Ab[1], acc1, tile0 + 1, m0 + 64)

#undef PACK_WRITE
#undef LOADB
#undef KSTEP
#undef COMPUTE_TILE
#undef EPILOGUE
}

// ---------------- K3: softmax over T per b -> weights (output) -------------
__global__ void k_softmax(const float* __restrict__ scores, float* __restrict__ wts) {
  __shared__ float rm[4], rs[4];
  int b = blockIdx.x, tid = threadIdx.x;
  float s[8];
#pragma unroll
  for (int i = 0; i < 8; ++i) s[i] = scores[b * T_ + i * 256 + tid];
  float mx = s[0];
#pragma unroll
  for (int i = 1; i < 8; ++i) mx = fmaxf(mx, s[i]);
#pragma unroll
  for (int off = 1; off <= 32; off <<= 1) mx = fmaxf(mx, __shfl_xor(mx, off));
  if ((tid & 63) == 0) rm[tid >> 6] = mx;
  __syncthreads();
  mx = fmaxf(fmaxf(rm[0], rm[1]), fmaxf(rm[2], rm[3]));
  float ex[8], se = 0.f;
#pragma unroll
  for (int i = 0; i < 8; ++i) { ex[i] = __expf(s[i] - mx); se += ex[i]; }
#pragma unroll
  for (int off = 1; off <= 32; off <<= 1) se += __shfl_xor(se, off);
  if ((tid & 63) == 0) rs[tid >> 6] = se;
  __syncthreads();
  se = rs[0] + rs[1] + rs[2] + rs[3];
  float inv = 1.0f / se;
#pragma unroll
  for (int i = 0; i < 8; ++i) wts[b * T_ + i * 256 + tid] = ex[i] * inv;
}

// ---------------- K4: flash recombine partial contexts -> context ----------
__global__ void k_ctx_comb(const float* __restrict__ part, const float* __restrict__ mz,
                           float* __restrict__ ctx) {
  __shared__ float sM[32], sZ[32];
  int b = blockIdx.x, tid = threadIdx.x;  // 512 threads, thread = h
  if (tid < 32) {
    sM[tid] = mz[(b * 32 + tid) * 2];
    sZ[tid] = mz[(b * 32 + tid) * 2 + 1];
  }
  __syncthreads();
  float M = sM[0];
#pragma unroll
  for (int i = 1; i < 32; ++i) M = fmaxf(M, sM[i]);
  float denom = 0.f;
#pragma unroll
  for (int i = 0; i < 32; ++i) denom += sZ[i] * __expf(sM[i] - M);
  float s = 0.f;
#pragma unroll
  for (int i = 0; i < 32; ++i)
    s += part[((size_t)b * 32 + i) * 512 + tid] * __expf(sM[i] - M);
  ctx[b * 512 + tid] = s / denom;
}

extern "C" void kernel_launch(void* const* d_in, const int* in_sizes, int n_in,
                              void* d_out, int out_size, void* d_ws, size_t ws_size,
                              hipStream_t stream) {
  const float* enc  = (const float*)d_in[0];
  const float* dec  = (const float*)d_in[1];
  const float* Wenc = (const float*)d_in[2];
  const float* Wdec = (const float*)d_in[3];
  const float* V    = (const float*)d_in[4];
  float* out = (float*)d_out;
  char* ws = (char*)d_ws;

  u16* wsB      = (u16*)ws;                            // 512 KB bf16 tiled W_enc
  float* dpj    = (float*)(ws + 512 * 1024);           // 128 KB dec_proj
  float* scores = (float*)(ws + 640 * 1024);           // 512 KB scores
  float* part   = (float*)(ws + 1152 * 1024);          // 4 MB ctx partials (2048 x 512)
  float* mz     = (float*)(ws + 1152 * 1024 + 4 * 1024 * 1024);  // 16 KB (m,Z)

  float* ctx = out;            // [B,H] = 32768 floats
  float* wts = out + B_ * H_;  // [B,T] = 131072 floats

  hipLaunchKernelGGL(k_prep, dim3(640), dim3(256), 0, stream, Wenc, wsB, dec, Wdec, dpj);
  hipLaunchKernelGGL(k_scores, dim3(1024), dim3(512), 0, stream, enc, wsB, dpj, V,
                     scores, part, mz);
  hipLaunchKernelGGL(k_softmax, dim3(64), dim3(256), 0, stream, scores, wts);
  hipLaunchKernelGGL(k_ctx_comb, dim3(64), dim3(512), 0, stream, part, mz, ctx);
}